// Round 9
// baseline (118.344 us; speedup 1.0000x reference)
//
#include <hip/hip_runtime.h>

// Per-token head-attention: B*S = 8192 independent tokens, each does
//   S = Q K^T / sqrt(128) (32x32 over heads), P = softmax_rows(S), O = P V.
// One wave owns one token.
// R9: ALL global traffic non-temporal (Q,K,V loads + LDS-transposed exact
// O stores) -- bypass the service-rate-capped L2/L3 path entirely and let
// HBM's 6.3 TB/s stream path serve the whole 537 MB.

typedef __bf16 bf16x8 __attribute__((ext_vector_type(8)));
typedef __bf16 bf16x2 __attribute__((ext_vector_type(2)));
typedef float  f32x4  __attribute__((ext_vector_type(4)));

static constexpr float kScale = 0.08838834764831845f;  // 1/sqrt(128)

__global__ __launch_bounds__(256) void attn_headwise(
    const float* __restrict__ q, const float* __restrict__ k,
    const float* __restrict__ v, float* __restrict__ out, int ntok) {
  const int wave = threadIdx.x >> 6;
  const int lane = threadIdx.x & 63;
  const int lr   = lane & 15;   // row/col-in-tile part
  const int G    = lane >> 4;   // lane group 0..3

  const long token = (long)blockIdx.x * 4 + wave;
  if (token >= ntok) return;
  const float* qt = q + token * 4096;
  const float* kt = k + token * 4096;
  const float* vt = v + token * 4096;
  float*       ot = out + token * 4096;

  // per-wave P buffer (bf16 32x32) + O half-buffer (32 rows x 64 f32, swizzled)
  __shared__ __align__(16) unsigned int pbuf[4][32 * 16];
  __shared__ __align__(16) float        obuf[4][32 * 64];
  unsigned int* pl = pbuf[wave];
  float*        ob = obuf[wave];

  // ---------------- S^T[g][h] = sum_d K[g][d] * Q[h][d] ----------------
  f32x4 acc[2][2];
  acc[0][0] = 0.f; acc[0][1] = 0.f; acc[1][0] = 0.f; acc[1][1] = 0.f;

  #pragma unroll
  for (int kk = 0; kk < 4; ++kk) {
    bf16x8 af[2], bq[2];
    #pragma unroll
    for (int gi = 0; gi < 2; ++gi) {
      const float* p = kt + (16 * gi + lr) * 128 + 32 * kk + 8 * G;
      f32x4 u0 = __builtin_nontemporal_load((const f32x4*)p);
      f32x4 u1 = __builtin_nontemporal_load((const f32x4*)(p + 4));
      bf16x8 f;
      f[0] = (__bf16)u0[0]; f[1] = (__bf16)u0[1];
      f[2] = (__bf16)u0[2]; f[3] = (__bf16)u0[3];
      f[4] = (__bf16)u1[0]; f[5] = (__bf16)u1[1];
      f[6] = (__bf16)u1[2]; f[7] = (__bf16)u1[3];
      af[gi] = f;
    }
    #pragma unroll
    for (int hj = 0; hj < 2; ++hj) {
      const float* p = qt + (16 * hj + lr) * 128 + 32 * kk + 8 * G;
      f32x4 u0 = __builtin_nontemporal_load((const f32x4*)p);
      f32x4 u1 = __builtin_nontemporal_load((const f32x4*)(p + 4));
      bf16x8 f;
      f[0] = (__bf16)u0[0]; f[1] = (__bf16)u0[1];
      f[2] = (__bf16)u0[2]; f[3] = (__bf16)u0[3];
      f[4] = (__bf16)u1[0]; f[5] = (__bf16)u1[1];
      f[6] = (__bf16)u1[2]; f[7] = (__bf16)u1[3];
      bq[hj] = f;
    }
    #pragma unroll
    for (int gi = 0; gi < 2; ++gi)
      #pragma unroll
      for (int hj = 0; hj < 2; ++hj)
        acc[gi][hj] = __builtin_amdgcn_mfma_f32_16x16x32_bf16(
            af[gi], bq[hj], acc[gi][hj], 0, 0, 0);
  }

  // ---------------- softmax over g (rows of S^T), per column h ----------
  #pragma unroll
  for (int hj = 0; hj < 2; ++hj) {
    float m = acc[0][hj][0];
    #pragma unroll
    for (int gi = 0; gi < 2; ++gi)
      #pragma unroll
      for (int r = 0; r < 4; ++r) m = fmaxf(m, acc[gi][hj][r]);
    m = fmaxf(m, __shfl_xor(m, 16, 64));
    m = fmaxf(m, __shfl_xor(m, 32, 64));

    float pv[2][4];
    float s = 0.f;
    #pragma unroll
    for (int gi = 0; gi < 2; ++gi)
      #pragma unroll
      for (int r = 0; r < 4; ++r) {
        float e = __expf((acc[gi][hj][r] - m) * kScale);
        pv[gi][r] = e;
        s += e;
      }
    s += __shfl_xor(s, 16, 64);
    s += __shfl_xor(s, 32, 64);
    float inv = 1.0f / s;

    #pragma unroll
    for (int gi = 0; gi < 2; ++gi)
      #pragma unroll
      for (int mp = 0; mp < 2; ++mp) {
        bf16x2 t;
        t[0] = (__bf16)(pv[gi][2 * mp]     * inv);
        t[1] = (__bf16)(pv[gi][2 * mp + 1] * inv);
        pl[(16 * hj + lr) * 16 + 8 * gi + 2 * G + mp] =
            __builtin_bit_cast(unsigned int, t);
      }
  }

  // ---------------- read P fragments (B-operand) -------------------------
  bf16x8 pf[2];
  #pragma unroll
  for (int ht = 0; ht < 2; ++ht)
    pf[ht] = *(const bf16x8*)&pl[(16 * ht + lr) * 16 + 4 * G];

  // ---------------- O^T = V^T * P^T, LDS-transposed nt stores ------------
  f32x4 zero = 0.f;
  #pragma unroll
  for (int half = 0; half < 2; ++half) {
    #pragma unroll
    for (int dtl = 0; dtl < 4; ++dtl) {
      const int dt = 4 * half + dtl;
      const float* vp = vt + 8 * G * 128 + 16 * dt + lr;
      bf16x8 vf;
      #pragma unroll
      for (int e = 0; e < 8; ++e)
        vf[e] = (__bf16)__builtin_nontemporal_load(vp + e * 128);
      f32x4 o0 = __builtin_amdgcn_mfma_f32_16x16x32_bf16(vf, pf[0], zero, 0, 0, 0);
      f32x4 o1 = __builtin_amdgcn_mfma_f32_16x16x32_bf16(vf, pf[1], zero, 0, 0, 0);
      const int c = 4 * dtl + G;
      const int r0 = lr, r1 = 16 + lr;
      *(f32x4*)&ob[r0 * 64 + ((c ^ (r0 & 7)) << 2)] = o0;
      *(f32x4*)&ob[r1 * 64 + ((c ^ (r1 & 7)) << 2)] = o1;
    }
    // flush: instr j writes rows 4j..4j+3, each 16-lane group a contiguous
    // 256B global segment (sector-complete, sequential)
    #pragma unroll
    for (int j = 0; j < 8; ++j) {
      const int row = 4 * j + (lane >> 4);
      const int cp  = lane & 15;
      f32x4 val = *(const f32x4*)&ob[row * 64 + ((cp ^ (row & 7)) << 2)];
      __builtin_nontemporal_store(val,
          (f32x4*)&ot[row * 128 + half * 64 + cp * 4]);
    }
  }
}

extern "C" void kernel_launch(void* const* d_in, const int* in_sizes, int n_in,
                              void* d_out, int out_size, void* d_ws, size_t ws_size,
                              hipStream_t stream) {
  const float* q = (const float*)d_in[0];
  const float* k = (const float*)d_in[1];
  const float* v = (const float*)d_in[2];
  float* out = (float*)d_out;
  int ntok = in_sizes[0] / 4096;          // B*S tokens (H*D = 4096)
  int grid = (ntok + 3) / 4;              // 4 waves (tokens) per 256-thread block
  hipLaunchKernelGGL(attn_headwise, dim3(grid), dim3(256), 0, stream,
                     q, k, v, out, ntok);
}

// Round 10
// 118.082 us; speedup vs baseline: 1.0022x; 1.0022x over previous
//
#include <hip/hip_runtime.h>

// Per-token head-attention: B*S = 8192 independent tokens, each does
//   S = Q K^T / sqrt(128)  (32x32 over heads), P = softmax_rows(S), O = P V.
// One wave (64 lanes) owns one token.
// R10 ablation: R7 with ONE factor flipped -- O stores back to cached
// (L2-merged) while keeping nt V loads (L3 dedicated to Q/K retention).

typedef __bf16 bf16x8 __attribute__((ext_vector_type(8)));
typedef __bf16 bf16x2 __attribute__((ext_vector_type(2)));
typedef float  f32x4  __attribute__((ext_vector_type(4)));

static constexpr float kScale = 0.08838834764831845f;  // 1/sqrt(128)

__global__ __launch_bounds__(256) void attn_headwise(
    const float* __restrict__ q, const float* __restrict__ k,
    const float* __restrict__ v, float* __restrict__ out, int ntok) {
  const int wave = threadIdx.x >> 6;
  const int lane = threadIdx.x & 63;
  const int lr   = lane & 15;   // row/col-in-tile part
  const int G    = lane >> 4;   // lane group 0..3

  const long token = (long)blockIdx.x * 4 + wave;
  if (token >= ntok) return;
  const float* qt = q + token * 4096;
  const float* kt = k + token * 4096;
  const float* vt = v + token * 4096;
  float*       ot = out + token * 4096;

  // per-wave P buffer: 32 rows (h) x 32 cols (g) bf16 = 32x16 dwords
  __shared__ __align__(16) unsigned int pbuf[4][32 * 16];
  unsigned int* pl = pbuf[wave];

  // ---------------- S^T[g][h] = sum_d K[g][d] * Q[h][d] ----------------
  f32x4 acc[2][2];
  acc[0][0] = 0.f; acc[0][1] = 0.f; acc[1][0] = 0.f; acc[1][1] = 0.f;

  #pragma unroll
  for (int kk = 0; kk < 4; ++kk) {
    bf16x8 af[2], bq[2];
    #pragma unroll
    for (int gi = 0; gi < 2; ++gi) {
      const float* p = kt + (16 * gi + lr) * 128 + 32 * kk + 8 * G;
      f32x4 u0 = *(const f32x4*)p;
      f32x4 u1 = *(const f32x4*)(p + 4);
      bf16x8 f;
      f[0] = (__bf16)u0[0]; f[1] = (__bf16)u0[1];
      f[2] = (__bf16)u0[2]; f[3] = (__bf16)u0[3];
      f[4] = (__bf16)u1[0]; f[5] = (__bf16)u1[1];
      f[6] = (__bf16)u1[2]; f[7] = (__bf16)u1[3];
      af[gi] = f;
    }
    #pragma unroll
    for (int hj = 0; hj < 2; ++hj) {
      const float* p = qt + (16 * hj + lr) * 128 + 32 * kk + 8 * G;
      f32x4 u0 = *(const f32x4*)p;
      f32x4 u1 = *(const f32x4*)(p + 4);
      bf16x8 f;
      f[0] = (__bf16)u0[0]; f[1] = (__bf16)u0[1];
      f[2] = (__bf16)u0[2]; f[3] = (__bf16)u0[3];
      f[4] = (__bf16)u1[0]; f[5] = (__bf16)u1[1];
      f[6] = (__bf16)u1[2]; f[7] = (__bf16)u1[3];
      bq[hj] = f;
    }
    #pragma unroll
    for (int gi = 0; gi < 2; ++gi)
      #pragma unroll
      for (int hj = 0; hj < 2; ++hj)
        acc[gi][hj] = __builtin_amdgcn_mfma_f32_16x16x32_bf16(
            af[gi], bq[hj], acc[gi][hj], 0, 0, 0);
  }

  // ---------------- softmax over g (rows of S^T), per column h ----------
  #pragma unroll
  for (int hj = 0; hj < 2; ++hj) {
    float m = acc[0][hj][0];
    #pragma unroll
    for (int gi = 0; gi < 2; ++gi)
      #pragma unroll
      for (int r = 0; r < 4; ++r) m = fmaxf(m, acc[gi][hj][r]);
    m = fmaxf(m, __shfl_xor(m, 16, 64));
    m = fmaxf(m, __shfl_xor(m, 32, 64));

    float pv[2][4];
    float s = 0.f;
    #pragma unroll
    for (int gi = 0; gi < 2; ++gi)
      #pragma unroll
      for (int r = 0; r < 4; ++r) {
        float e = __expf((acc[gi][hj][r] - m) * kScale);
        pv[gi][r] = e;
        s += e;
      }
    s += __shfl_xor(s, 16, 64);
    s += __shfl_xor(s, 32, 64);
    float inv = 1.0f / s;

    #pragma unroll
    for (int gi = 0; gi < 2; ++gi)
      #pragma unroll
      for (int mp = 0; mp < 2; ++mp) {
        bf16x2 t;
        t[0] = (__bf16)(pv[gi][2 * mp]     * inv);
        t[1] = (__bf16)(pv[gi][2 * mp + 1] * inv);
        pl[(16 * hj + lr) * 16 + 8 * gi + 2 * G + mp] =
            __builtin_bit_cast(unsigned int, t);
      }
  }

  // ---------------- read P fragments (B-operand) -------------------------
  bf16x8 pf[2];
  #pragma unroll
  for (int ht = 0; ht < 2; ++ht)
    pf[ht] = *(const bf16x8*)&pl[(16 * ht + lr) * 16 + 4 * G];

  // ---------------- O^T = V^T * P^T  (V nt; stores cached/L2-merged) -----
  f32x4 zero = 0.f;
  #pragma unroll
  for (int dt = 0; dt < 8; ++dt) {
    const float* vp = vt + 8 * G * 128 + 16 * dt + lr;
    bf16x8 vf;
    #pragma unroll
    for (int e = 0; e < 8; ++e)
      vf[e] = (__bf16)__builtin_nontemporal_load(vp + e * 128);
    f32x4 o0 = __builtin_amdgcn_mfma_f32_16x16x32_bf16(vf, pf[0], zero, 0, 0, 0);
    f32x4 o1 = __builtin_amdgcn_mfma_f32_16x16x32_bf16(vf, pf[1], zero, 0, 0, 0);
    *(f32x4*)&ot[lr * 128 + 16 * dt + 4 * G]        = o0;
    *(f32x4*)&ot[(16 + lr) * 128 + 16 * dt + 4 * G] = o1;
  }
}

extern "C" void kernel_launch(void* const* d_in, const int* in_sizes, int n_in,
                              void* d_out, int out_size, void* d_ws, size_t ws_size,
                              hipStream_t stream) {
  const float* q = (const float*)d_in[0];
  const float* k = (const float*)d_in[1];
  const float* v = (const float*)d_in[2];
  float* out = (float*)d_out;
  int ntok = in_sizes[0] / 4096;          // B*S tokens (H*D = 4096)
  int grid = (ntok + 3) / 4;              // 4 waves (tokens) per 256-thread block
  hipLaunchKernelGGL(attn_headwise, dim3(grid), dim3(256), 0, stream,
                     q, k, v, out, ntok);
}

// Round 11
// 113.532 us; speedup vs baseline: 1.0424x; 1.0401x over previous
//
#include <hip/hip_runtime.h>

// Per-token head-attention: B*S = 8192 independent tokens, each does
//   S = Q K^T / sqrt(128)  (32x32 over heads), P = softmax_rows(S), O = P V.
// One wave (64 lanes) owns one token.
// R11 ablation (completes the 2x2 matrix): cached Q/K/V loads (full L3
// read retention) + NON-TEMPORAL direct O stores (dead output lines never
// allocate in L2/L3 -> no read eviction, no double write work).

typedef __bf16 bf16x8 __attribute__((ext_vector_type(8)));
typedef __bf16 bf16x2 __attribute__((ext_vector_type(2)));
typedef float  f32x4  __attribute__((ext_vector_type(4)));

static constexpr float kScale = 0.08838834764831845f;  // 1/sqrt(128)

__global__ __launch_bounds__(256) void attn_headwise(
    const float* __restrict__ q, const float* __restrict__ k,
    const float* __restrict__ v, float* __restrict__ out, int ntok) {
  const int wave = threadIdx.x >> 6;
  const int lane = threadIdx.x & 63;
  const int lr   = lane & 15;   // row/col-in-tile part
  const int G    = lane >> 4;   // lane group 0..3

  const long token = (long)blockIdx.x * 4 + wave;
  if (token >= ntok) return;
  const float* qt = q + token * 4096;
  const float* kt = k + token * 4096;
  const float* vt = v + token * 4096;
  float*       ot = out + token * 4096;

  // per-wave P buffer: 32 rows (h) x 32 cols (g) bf16 = 32x16 dwords
  __shared__ __align__(16) unsigned int pbuf[4][32 * 16];
  unsigned int* pl = pbuf[wave];

  // ---------------- S^T[g][h] = sum_d K[g][d] * Q[h][d] ----------------
  f32x4 acc[2][2];
  acc[0][0] = 0.f; acc[0][1] = 0.f; acc[1][0] = 0.f; acc[1][1] = 0.f;

  #pragma unroll
  for (int kk = 0; kk < 4; ++kk) {
    bf16x8 af[2], bq[2];
    #pragma unroll
    for (int gi = 0; gi < 2; ++gi) {
      const float* p = kt + (16 * gi + lr) * 128 + 32 * kk + 8 * G;
      f32x4 u0 = *(const f32x4*)p;
      f32x4 u1 = *(const f32x4*)(p + 4);
      bf16x8 f;
      f[0] = (__bf16)u0[0]; f[1] = (__bf16)u0[1];
      f[2] = (__bf16)u0[2]; f[3] = (__bf16)u0[3];
      f[4] = (__bf16)u1[0]; f[5] = (__bf16)u1[1];
      f[6] = (__bf16)u1[2]; f[7] = (__bf16)u1[3];
      af[gi] = f;
    }
    #pragma unroll
    for (int hj = 0; hj < 2; ++hj) {
      const float* p = qt + (16 * hj + lr) * 128 + 32 * kk + 8 * G;
      f32x4 u0 = *(const f32x4*)p;
      f32x4 u1 = *(const f32x4*)(p + 4);
      bf16x8 f;
      f[0] = (__bf16)u0[0]; f[1] = (__bf16)u0[1];
      f[2] = (__bf16)u0[2]; f[3] = (__bf16)u0[3];
      f[4] = (__bf16)u1[0]; f[5] = (__bf16)u1[1];
      f[6] = (__bf16)u1[2]; f[7] = (__bf16)u1[3];
      bq[hj] = f;
    }
    #pragma unroll
    for (int gi = 0; gi < 2; ++gi)
      #pragma unroll
      for (int hj = 0; hj < 2; ++hj)
        acc[gi][hj] = __builtin_amdgcn_mfma_f32_16x16x32_bf16(
            af[gi], bq[hj], acc[gi][hj], 0, 0, 0);
  }

  // ---------------- softmax over g (rows of S^T), per column h ----------
  #pragma unroll
  for (int hj = 0; hj < 2; ++hj) {
    float m = acc[0][hj][0];
    #pragma unroll
    for (int gi = 0; gi < 2; ++gi)
      #pragma unroll
      for (int r = 0; r < 4; ++r) m = fmaxf(m, acc[gi][hj][r]);
    m = fmaxf(m, __shfl_xor(m, 16, 64));
    m = fmaxf(m, __shfl_xor(m, 32, 64));

    float pv[2][4];
    float s = 0.f;
    #pragma unroll
    for (int gi = 0; gi < 2; ++gi)
      #pragma unroll
      for (int r = 0; r < 4; ++r) {
        float e = __expf((acc[gi][hj][r] - m) * kScale);
        pv[gi][r] = e;
        s += e;
      }
    s += __shfl_xor(s, 16, 64);
    s += __shfl_xor(s, 32, 64);
    float inv = 1.0f / s;

    #pragma unroll
    for (int gi = 0; gi < 2; ++gi)
      #pragma unroll
      for (int mp = 0; mp < 2; ++mp) {
        bf16x2 t;
        t[0] = (__bf16)(pv[gi][2 * mp]     * inv);
        t[1] = (__bf16)(pv[gi][2 * mp + 1] * inv);
        pl[(16 * hj + lr) * 16 + 8 * gi + 2 * G + mp] =
            __builtin_bit_cast(unsigned int, t);
      }
  }

  // ---------------- read P fragments (B-operand) -------------------------
  bf16x8 pf[2];
  #pragma unroll
  for (int ht = 0; ht < 2; ++ht)
    pf[ht] = *(const bf16x8*)&pl[(16 * ht + lr) * 16 + 4 * G];

  // ---------------- O^T = V^T * P^T (cached V loads; nt direct stores) ---
  f32x4 zero = 0.f;
  #pragma unroll
  for (int dt = 0; dt < 8; ++dt) {
    const float* vp = vt + 8 * G * 128 + 16 * dt + lr;
    bf16x8 vf;
    #pragma unroll
    for (int e = 0; e < 8; ++e)
      vf[e] = (__bf16)vp[e * 128];
    f32x4 o0 = __builtin_amdgcn_mfma_f32_16x16x32_bf16(vf, pf[0], zero, 0, 0, 0);
    f32x4 o1 = __builtin_amdgcn_mfma_f32_16x16x32_bf16(vf, pf[1], zero, 0, 0, 0);
    __builtin_nontemporal_store(o0, (f32x4*)&ot[lr * 128 + 16 * dt + 4 * G]);
    __builtin_nontemporal_store(o1, (f32x4*)&ot[(16 + lr) * 128 + 16 * dt + 4 * G]);
  }
}

extern "C" void kernel_launch(void* const* d_in, const int* in_sizes, int n_in,
                              void* d_out, int out_size, void* d_ws, size_t ws_size,
                              hipStream_t stream) {
  const float* q = (const float*)d_in[0];
  const float* k = (const float*)d_in[1];
  const float* v = (const float*)d_in[2];
  float* out = (float*)d_out;
  int ntok = in_sizes[0] / 4096;          // B*S tokens (H*D = 4096)
  int grid = (ntok + 3) / 4;              // 4 waves (tokens) per 256-thread block
  hipLaunchKernelGGL(attn_headwise, dim3(grid), dim3(256), 0, stream,
                     q, k, v, out, ntok);
}

// Round 12
// 111.760 us; speedup vs baseline: 1.0589x; 1.0159x over previous
//
#include <hip/hip_runtime.h>

// Per-token head-attention: B*S = 8192 independent tokens, each does
//   S = Q K^T / sqrt(128)  (32x32 over heads), P = softmax_rows(S), O = P V.
// One wave (64 lanes) owns one token.
// R11 ablation (completes the 2x2 matrix): cached Q/K/V loads (full L3
// read retention) + NON-TEMPORAL direct O stores (dead output lines never
// allocate in L2/L3 -> no read eviction, no double write work).

typedef __bf16 bf16x8 __attribute__((ext_vector_type(8)));
typedef __bf16 bf16x2 __attribute__((ext_vector_type(2)));
typedef float  f32x4  __attribute__((ext_vector_type(4)));

static constexpr float kScale = 0.08838834764831845f;  // 1/sqrt(128)

__global__ __launch_bounds__(256) void attn_headwise(
    const float* __restrict__ q, const float* __restrict__ k,
    const float* __restrict__ v, float* __restrict__ out, int ntok) {
  const int wave = threadIdx.x >> 6;
  const int lane = threadIdx.x & 63;
  const int lr   = lane & 15;   // row/col-in-tile part
  const int G    = lane >> 4;   // lane group 0..3

  const long token = (long)blockIdx.x * 4 + wave;
  if (token >= ntok) return;
  const float* qt = q + token * 4096;
  const float* kt = k + token * 4096;
  const float* vt = v + token * 4096;
  float*       ot = out + token * 4096;

  // per-wave P buffer: 32 rows (h) x 32 cols (g) bf16 = 32x16 dwords
  __shared__ __align__(16) unsigned int pbuf[4][32 * 16];
  unsigned int* pl = pbuf[wave];

  // ---------------- S^T[g][h] = sum_d K[g][d] * Q[h][d] ----------------
  f32x4 acc[2][2];
  acc[0][0] = 0.f; acc[0][1] = 0.f; acc[1][0] = 0.f; acc[1][1] = 0.f;

  #pragma unroll
  for (int kk = 0; kk < 4; ++kk) {
    bf16x8 af[2], bq[2];
    #pragma unroll
    for (int gi = 0; gi < 2; ++gi) {
      const float* p = kt + (16 * gi + lr) * 128 + 32 * kk + 8 * G;
      f32x4 u0 = *(const f32x4*)p;
      f32x4 u1 = *(const f32x4*)(p + 4);
      bf16x8 f;
      f[0] = (__bf16)u0[0]; f[1] = (__bf16)u0[1];
      f[2] = (__bf16)u0[2]; f[3] = (__bf16)u0[3];
      f[4] = (__bf16)u1[0]; f[5] = (__bf16)u1[1];
      f[6] = (__bf16)u1[2]; f[7] = (__bf16)u1[3];
      af[gi] = f;
    }
    #pragma unroll
    for (int hj = 0; hj < 2; ++hj) {
      const float* p = qt + (16 * hj + lr) * 128 + 32 * kk + 8 * G;
      f32x4 u0 = *(const f32x4*)p;
      f32x4 u1 = *(const f32x4*)(p + 4);
      bf16x8 f;
      f[0] = (__bf16)u0[0]; f[1] = (__bf16)u0[1];
      f[2] = (__bf16)u0[2]; f[3] = (__bf16)u0[3];
      f[4] = (__bf16)u1[0]; f[5] = (__bf16)u1[1];
      f[6] = (__bf16)u1[2]; f[7] = (__bf16)u1[3];
      bq[hj] = f;
    }
    #pragma unroll
    for (int gi = 0; gi < 2; ++gi)
      #pragma unroll
      for (int hj = 0; hj < 2; ++hj)
        acc[gi][hj] = __builtin_amdgcn_mfma_f32_16x16x32_bf16(
            af[gi], bq[hj], acc[gi][hj], 0, 0, 0);
  }

  // ---------------- softmax over g (rows of S^T), per column h ----------
  #pragma unroll
  for (int hj = 0; hj < 2; ++hj) {
    float m = acc[0][hj][0];
    #pragma unroll
    for (int gi = 0; gi < 2; ++gi)
      #pragma unroll
      for (int r = 0; r < 4; ++r) m = fmaxf(m, acc[gi][hj][r]);
    m = fmaxf(m, __shfl_xor(m, 16, 64));
    m = fmaxf(m, __shfl_xor(m, 32, 64));

    float pv[2][4];
    float s = 0.f;
    #pragma unroll
    for (int gi = 0; gi < 2; ++gi)
      #pragma unroll
      for (int r = 0; r < 4; ++r) {
        float e = __expf((acc[gi][hj][r] - m) * kScale);
        pv[gi][r] = e;
        s += e;
      }
    s += __shfl_xor(s, 16, 64);
    s += __shfl_xor(s, 32, 64);
    float inv = 1.0f / s;

    #pragma unroll
    for (int gi = 0; gi < 2; ++gi)
      #pragma unroll
      for (int mp = 0; mp < 2; ++mp) {
        bf16x2 t;
        t[0] = (__bf16)(pv[gi][2 * mp]     * inv);
        t[1] = (__bf16)(pv[gi][2 * mp + 1] * inv);
        pl[(16 * hj + lr) * 16 + 8 * gi + 2 * G + mp] =
            __builtin_bit_cast(unsigned int, t);
      }
  }

  // ---------------- read P fragments (B-operand) -------------------------
  bf16x8 pf[2];
  #pragma unroll
  for (int ht = 0; ht < 2; ++ht)
    pf[ht] = *(const bf16x8*)&pl[(16 * ht + lr) * 16 + 4 * G];

  // ---------------- O^T = V^T * P^T (cached V loads; nt direct stores) ---
  f32x4 zero = 0.f;
  #pragma unroll
  for (int dt = 0; dt < 8; ++dt) {
    const float* vp = vt + 8 * G * 128 + 16 * dt + lr;
    bf16x8 vf;
    #pragma unroll
    for (int e = 0; e < 8; ++e)
      vf[e] = (__bf16)vp[e * 128];
    f32x4 o0 = __builtin_amdgcn_mfma_f32_16x16x32_bf16(vf, pf[0], zero, 0, 0, 0);
    f32x4 o1 = __builtin_amdgcn_mfma_f32_16x16x32_bf16(vf, pf[1], zero, 0, 0, 0);
    __builtin_nontemporal_store(o0, (f32x4*)&ot[lr * 128 + 16 * dt + 4 * G]);
    __builtin_nontemporal_store(o1, (f32x4*)&ot[(16 + lr) * 128 + 16 * dt + 4 * G]);
  }
}

extern "C" void kernel_launch(void* const* d_in, const int* in_sizes, int n_in,
                              void* d_out, int out_size, void* d_ws, size_t ws_size,
                              hipStream_t stream) {
  const float* q = (const float*)d_in[0];
  const float* k = (const float*)d_in[1];
  const float* v = (const float*)d_in[2];
  float* out = (float*)d_out;
  int ntok = in_sizes[0] / 4096;          // B*S tokens (H*D = 4096)
  int grid = (ntok + 3) / 4;              // 4 waves (tokens) per 256-thread block
  hipLaunchKernelGGL(attn_headwise, dim3(grid), dim3(256), 0, stream,
                     q, k, v, out, ntok);
}

// Round 13
// 101.204 us; speedup vs baseline: 1.1694x; 1.1043x over previous
//
#include <hip/hip_runtime.h>

// Per-token head-attention: B*S = 8192 independent tokens, each does
//   S = Q K^T / sqrt(128)  (32x32 over heads), P = softmax_rows(S), O = P V.
// One wave (64 lanes) owns one token.
// FINAL (= R7 winner, 100.25 us): cached Q/K loads (L3 retains ~72% across
// replays) + non-temporal V loads AND non-temporal direct O stores. The
// nt-V/nt-O combination moves the whole PV-phase traffic off the contended
// L2/L3 path (which then serves only Q/K) onto HBM's stream path.
// Measured matrix: cached/cached 113.4, ntV/cached 118.1, cached/ntSt 111.8,
// ntV/ntSt 100.25 (this), +LDS-exact-stores 104.1, all-nt 118.3.

typedef __bf16 bf16x8 __attribute__((ext_vector_type(8)));
typedef __bf16 bf16x2 __attribute__((ext_vector_type(2)));
typedef float  f32x4  __attribute__((ext_vector_type(4)));

static constexpr float kScale = 0.08838834764831845f;  // 1/sqrt(128)

__global__ __launch_bounds__(256) void attn_headwise(
    const float* __restrict__ q, const float* __restrict__ k,
    const float* __restrict__ v, float* __restrict__ out, int ntok) {
  const int wave = threadIdx.x >> 6;
  const int lane = threadIdx.x & 63;
  const int lr   = lane & 15;   // row/col-in-tile part
  const int G    = lane >> 4;   // lane group 0..3

  const long token = (long)blockIdx.x * 4 + wave;
  if (token >= ntok) return;
  const float* qt = q + token * 4096;
  const float* kt = k + token * 4096;
  const float* vt = v + token * 4096;
  float*       ot = out + token * 4096;

  // per-wave P buffer: 32 rows (h) x 32 cols (g) bf16 = 32x16 dwords
  __shared__ __align__(16) unsigned int pbuf[4][32 * 16];
  unsigned int* pl = pbuf[wave];

  // ---------------- S^T[g][h] = sum_d K[g][d] * Q[h][d] ----------------
  f32x4 acc[2][2];
  acc[0][0] = 0.f; acc[0][1] = 0.f; acc[1][0] = 0.f; acc[1][1] = 0.f;

  #pragma unroll
  for (int kk = 0; kk < 4; ++kk) {
    bf16x8 af[2], bq[2];
    #pragma unroll
    for (int gi = 0; gi < 2; ++gi) {
      const float* p = kt + (16 * gi + lr) * 128 + 32 * kk + 8 * G;
      f32x4 u0 = *(const f32x4*)p;
      f32x4 u1 = *(const f32x4*)(p + 4);
      bf16x8 f;
      f[0] = (__bf16)u0[0]; f[1] = (__bf16)u0[1];
      f[2] = (__bf16)u0[2]; f[3] = (__bf16)u0[3];
      f[4] = (__bf16)u1[0]; f[5] = (__bf16)u1[1];
      f[6] = (__bf16)u1[2]; f[7] = (__bf16)u1[3];
      af[gi] = f;
    }
    #pragma unroll
    for (int hj = 0; hj < 2; ++hj) {
      const float* p = qt + (16 * hj + lr) * 128 + 32 * kk + 8 * G;
      f32x4 u0 = *(const f32x4*)p;
      f32x4 u1 = *(const f32x4*)(p + 4);
      bf16x8 f;
      f[0] = (__bf16)u0[0]; f[1] = (__bf16)u0[1];
      f[2] = (__bf16)u0[2]; f[3] = (__bf16)u0[3];
      f[4] = (__bf16)u1[0]; f[5] = (__bf16)u1[1];
      f[6] = (__bf16)u1[2]; f[7] = (__bf16)u1[3];
      bq[hj] = f;
    }
    #pragma unroll
    for (int gi = 0; gi < 2; ++gi)
      #pragma unroll
      for (int hj = 0; hj < 2; ++hj)
        acc[gi][hj] = __builtin_amdgcn_mfma_f32_16x16x32_bf16(
            af[gi], bq[hj], acc[gi][hj], 0, 0, 0);
  }

  // ---------------- softmax over g (rows of S^T), per column h ----------
  #pragma unroll
  for (int hj = 0; hj < 2; ++hj) {
    float m = acc[0][hj][0];
    #pragma unroll
    for (int gi = 0; gi < 2; ++gi)
      #pragma unroll
      for (int r = 0; r < 4; ++r) m = fmaxf(m, acc[gi][hj][r]);
    m = fmaxf(m, __shfl_xor(m, 16, 64));
    m = fmaxf(m, __shfl_xor(m, 32, 64));

    float pv[2][4];
    float s = 0.f;
    #pragma unroll
    for (int gi = 0; gi < 2; ++gi)
      #pragma unroll
      for (int r = 0; r < 4; ++r) {
        float e = __expf((acc[gi][hj][r] - m) * kScale);
        pv[gi][r] = e;
        s += e;
      }
    s += __shfl_xor(s, 16, 64);
    s += __shfl_xor(s, 32, 64);
    float inv = 1.0f / s;

    #pragma unroll
    for (int gi = 0; gi < 2; ++gi)
      #pragma unroll
      for (int mp = 0; mp < 2; ++mp) {
        bf16x2 t;
        t[0] = (__bf16)(pv[gi][2 * mp]     * inv);
        t[1] = (__bf16)(pv[gi][2 * mp + 1] * inv);
        pl[(16 * hj + lr) * 16 + 8 * gi + 2 * G + mp] =
            __builtin_bit_cast(unsigned int, t);
      }
  }

  // ---------------- read P fragments (B-operand) -------------------------
  bf16x8 pf[2];
  #pragma unroll
  for (int ht = 0; ht < 2; ++ht)
    pf[ht] = *(const bf16x8*)&pl[(16 * ht + lr) * 16 + 4 * G];

  // ---------------- O^T = V^T * P^T  (nt V loads; nt direct stores) ------
  f32x4 zero = 0.f;
  #pragma unroll
  for (int dt = 0; dt < 8; ++dt) {
    const float* vp = vt + 8 * G * 128 + 16 * dt + lr;
    bf16x8 vf;
    #pragma unroll
    for (int e = 0; e < 8; ++e)
      vf[e] = (__bf16)__builtin_nontemporal_load(vp + e * 128);
    f32x4 o0 = __builtin_amdgcn_mfma_f32_16x16x32_bf16(vf, pf[0], zero, 0, 0, 0);
    f32x4 o1 = __builtin_amdgcn_mfma_f32_16x16x32_bf16(vf, pf[1], zero, 0, 0, 0);
    __builtin_nontemporal_store(o0, (f32x4*)&ot[lr * 128 + 16 * dt + 4 * G]);
    __builtin_nontemporal_store(o1, (f32x4*)&ot[(16 + lr) * 128 + 16 * dt + 4 * G]);
  }
}

extern "C" void kernel_launch(void* const* d_in, const int* in_sizes, int n_in,
                              void* d_out, int out_size, void* d_ws, size_t ws_size,
                              hipStream_t stream) {
  const float* q = (const float*)d_in[0];
  const float* k = (const float*)d_in[1];
  const float* v = (const float*)d_in[2];
  float* out = (float*)d_out;
  int ntok = in_sizes[0] / 4096;          // B*S tokens (H*D = 4096)
  int grid = (ntok + 3) / 4;              // 4 waves (tokens) per 256-thread block
  hipLaunchKernelGGL(attn_headwise, dim3(grid), dim3(256), 0, stream,
                     q, k, v, out, ntok);
}